// Round 13
// baseline (56.875 us; speedup 1.0000x reference)
//
#include <hip/hip_runtime.h>

// Depthwise temporal FIR (FW=64, SAME pad low=31/high=32), weight-norm +
// positivity clamp + bias. out[t,c] = b[c] + sum_f relu(w[f,c]/||w||) x[t-31+f,c]
//
// Round-13: 4-way tap split (grp = lane>>4 owns taps 16g..16g+15 of the same
// 16 channels) with SYSTOLIC RING reduction: at step s, group g computes the
// partial of output t = t0+s-g (windows skewed by 15g); the running sum hops
// g-1 -> g via ONE ds_bpermute per step; group 3 stores one row per step.
// Live set ~60 VGPR (< 64) -> no allocator squeeze (R6-R12 lesson: live>64
// always got parked in AGPRs at ~2x VALU bloat). c-fastest grid (R11 lesson),
// 2048 blocks (R8/R10 lesson: occupancy needs >= 8 blocks/CU).

#define T_DIM 4096
#define C_DIM 4096
#define PAD_L 31
#define TPG   16      // taps per group (lane)
#define KTILE 128     // output rows per block
#define CB    64      // channels per block (4 waves x 16)
#define NPER  (KTILE / 16)

template <bool GUARD>
__device__ __forceinline__ void fir_body(const float* __restrict__ x,
                                         const float* __restrict__ w,
                                         const float* __restrict__ bia,
                                         float* __restrict__ out,
                                         int c, int grp, int t0) {
    const float* __restrict__ xp = x + c;                 // channel column base

    // ---- weights of this lane's tap group; weight-norm across 4 groups ----
    float wf[TPG];
    float ss = 0.0f;
#pragma unroll
    for (int j = 0; j < TPG; ++j) {
        wf[j] = w[(grp * TPG + j) * C_DIM + c];
        ss = fmaf(wf[j], wf[j], ss);
    }
    ss += __shfl_xor(ss, 16);
    ss += __shfl_xor(ss, 32);                             // full 64-tap norm
    const float inv = 1.0f / fmaxf(sqrtf(ss), 1e-8f);
#pragma unroll
    for (int j = 0; j < TPG; ++j) wf[j] = fmaxf(wf[j] * inv, 0.0f);

    const float bv = bia[c];

    // group g's skewed window: at step s it reads x[W0+s .. W0+s+15],
    // the partial of output t = t0 + s - g  (taps 16g..16g+15).
    const int W0 = t0 - PAD_L + 15 * grp;

#define LOADX(m) ((!GUARD || ((unsigned)(m) < (unsigned)T_DIM))               \
                      ? xp[(long long)(m) * C_DIM] : 0.0f)

    // ---- circular window: xbuf[(s+j)&15] = x[W0+s+j]; warm-up s=0 ----
    float xbuf[TPG];
#pragma unroll
    for (int i = 0; i < TPG; ++i) xbuf[i] = LOADX(W0 + i);

    // prefetch: pfA feeds inserts of steps kb+0..7, pfB steps kb+8..15
    float pfA[8], pfB[8];
#pragma unroll
    for (int i = 0; i < 8; ++i) pfA[i] = LOADX(W0 + 16 + i);
#pragma unroll
    for (int i = 0; i < 8; ++i) pfB[i] = LOADX(W0 + 24 + i);

    float R = 0.0f;                                       // ring running sum
    const int paddr = (((threadIdx.x & 63) + 48) & 63) << 2;  // lane-16 (mod 64), bytes
    const bool g0 = (grp == 0);
    const bool g3 = (grp == 3);
    float* __restrict__ op0 = out + (long long)t0 * C_DIM + c;

    // one ring step; k is compile-time (slot arithmetic static), kb runtime
#define FIR_STEP(k, src, SGATE)                                               \
    {                                                                         \
        float a0 = 0.0f, a1 = 0.0f;                                           \
        _Pragma("unroll")                                                     \
        for (int j = 0; j < TPG; j += 2) {                                    \
            a0 = fmaf(wf[j],     xbuf[((k) + j) & 15],     a0);               \
            a1 = fmaf(wf[j + 1], xbuf[((k) + j + 1) & 15], a1);               \
        }                                                                     \
        const float p1 = a0 + a1;                                             \
        const float pulled = __int_as_float(                                  \
            __builtin_amdgcn_ds_bpermute(paddr, __float_as_int(R)));          \
        R = (g0 ? bv : pulled) + p1;                                          \
        if ((SGATE) && g3)                                                    \
            __builtin_nontemporal_store(R,                                    \
                op0 + (long long)(kb + (k) - 3) * C_DIM);                     \
        xbuf[(k) & 15] = src[(k) & 7];                                        \
    }

    int kb = 0;
    // ---- peeled period 0: stores gated until the ring is primed (s >= 3) ----
    FIR_STEP(0, pfA, false) FIR_STEP(1, pfA, false) FIR_STEP(2, pfA, false)
    FIR_STEP(3, pfA, true)  FIR_STEP(4, pfA, true)  FIR_STEP(5, pfA, true)
    FIR_STEP(6, pfA, true)  FIR_STEP(7, pfA, true)
#pragma unroll
    for (int i = 0; i < 8; ++i) pfA[i] = LOADX(W0 + 32 + i);
    FIR_STEP(8, pfB, true)  FIR_STEP(9, pfB, true)  FIR_STEP(10, pfB, true)
    FIR_STEP(11, pfB, true) FIR_STEP(12, pfB, true) FIR_STEP(13, pfB, true)
    FIR_STEP(14, pfB, true) FIR_STEP(15, pfB, true)
#pragma unroll
    for (int i = 0; i < 8; ++i) pfB[i] = LOADX(W0 + 40 + i);

    // ---- main periods ----
#pragma unroll 1
    for (int p = 1; p < NPER; ++p) {
        kb = p * 16;
        FIR_STEP(0, pfA, true)  FIR_STEP(1, pfA, true)  FIR_STEP(2, pfA, true)
        FIR_STEP(3, pfA, true)  FIR_STEP(4, pfA, true)  FIR_STEP(5, pfA, true)
        FIR_STEP(6, pfA, true)  FIR_STEP(7, pfA, true)
#pragma unroll
        for (int i = 0; i < 8; ++i) pfA[i] = LOADX(W0 + kb + 32 + i);
        FIR_STEP(8, pfB, true)  FIR_STEP(9, pfB, true)  FIR_STEP(10, pfB, true)
        FIR_STEP(11, pfB, true) FIR_STEP(12, pfB, true) FIR_STEP(13, pfB, true)
        FIR_STEP(14, pfB, true) FIR_STEP(15, pfB, true)
        if (p < NPER - 1) {
#pragma unroll
            for (int i = 0; i < 8; ++i) pfB[i] = LOADX(W0 + kb + 40 + i);
        }
    }

    // ---- ring drain: s = KTILE..KTILE+2 complete rows KTILE-3..KTILE-1 ----
    kb = KTILE;
    FIR_STEP(0, pfA, true) FIR_STEP(1, pfA, true) FIR_STEP(2, pfA, true)

#undef FIR_STEP
#undef LOADX
}

__global__ __launch_bounds__(256) void depthwise_fir_kernel(
    const float* __restrict__ x, const float* __restrict__ w,
    const float* __restrict__ bia, float* __restrict__ out) {
    const int lane = threadIdx.x & 63;
    const int wave = threadIdx.x >> 6;
    const int grp  = lane >> 4;                  // tap group 0..3
    const int c    = blockIdx.x * CB + wave * 16 + (lane & 15);
    const int t0   = blockIdx.y * KTILE;
    // zero-pad guard only at first/last time tile (block-uniform branch)
    if (blockIdx.y == 0 || blockIdx.y == gridDim.y - 1)
        fir_body<true>(x, w, bia, out, c, grp, t0);
    else
        fir_body<false>(x, w, bia, out, c, grp, t0);
}

extern "C" void kernel_launch(void* const* d_in, const int* in_sizes, int n_in,
                              void* d_out, int out_size, void* d_ws, size_t ws_size,
                              hipStream_t stream) {
    const float* x = (const float*)d_in[0];   // [T, C]
    const float* w = (const float*)d_in[1];   // [FW, C]
    const float* b = (const float*)d_in[2];   // [C]
    float* out = (float*)d_out;               // [T, C]

    dim3 grid(C_DIM / CB, T_DIM / KTILE);     // 64 x 32 = 2048 blocks, c-fastest
    dim3 block(256);
    hipLaunchKernelGGL(depthwise_fir_kernel, grid, block, 0, stream, x, w, b, out);
}

// Round 14
// 48.835 us; speedup vs baseline: 1.1646x; 1.1646x over previous
//
#include <hip/hip_runtime.h>

// Depthwise temporal FIR (FW=64, SAME pad low=31/high=32), weight-norm +
// positivity clamp + bias. out[t,c] = b[c] + sum_f relu(w[f,c]/||w||) x[t-31+f,c]
//
// Round-14: PACKED fp32. Each lane owns 2 channels (float2) and uses
// v_pk_fma_f32 (2 FMA/lane/instr -> halves VALU issue, the only path to the
// 157TF fp32 rate). Wave g owns taps 16g..16g+15 (no shuffles, R12 lesson);
// partials go to ping-pong LDS slabs; reduce of slab S overlaps the FIR of
// slab S^1 (1 barrier per 8-row subtile). Live set ~108 regs pinned with
// waves_per_eu(4,4) (budget 128 -> nothing to squeeze; R6-R13 lesson).
// c-fastest grid (R11), 2048 blocks = 8/CU.

#define T_DIM 4096
#define C_DIM 4096
#define C2    2048          // row stride in float2
#define PAD_L 31
#define TPG   16            // taps per wave-group
#define KTILE 64            // output rows per block
#define SOFF_B 2048         // slab B offset (float2 units); A = 0

__device__ __forceinline__ float2 pkfma(float2 a, float2 b, float2 c) {
    float2 d;
    asm("v_pk_fma_f32 %0, %1, %2, %3" : "=v"(d) : "v"(a), "v"(b), "v"(c));
    return d;
}

template <bool GUARD>
__device__ __forceinline__ void fir_body(const float2* __restrict__ x2,
                                         const float2* __restrict__ w2,
                                         const float2* __restrict__ b2,
                                         float2* __restrict__ out2,
                                         float2* __restrict__ slab,
                                         int cq, int q, int g, int t0) {
    const float2* __restrict__ xp2 = x2 + cq;
    const int rp = 2 * g;                       // rows this wave reduces/stores

    // ---- weights of this wave's tap group; norm combined via LDS ----
    float2 wf[TPG];
    float ssx = 0.f, ssy = 0.f;
#pragma unroll
    for (int j = 0; j < TPG; ++j) {
        wf[j] = w2[(g * TPG + j) * C2 + cq];
        ssx = fmaf(wf[j].x, wf[j].x, ssx);
        ssy = fmaf(wf[j].y, wf[j].y, ssy);
    }
    slab[g * 64 + q] = make_float2(ssx, ssy);
    __syncthreads();
    {
        float2 s0 = slab[q], s1 = slab[64 + q], s2 = slab[128 + q], s3 = slab[192 + q];
        ssx = (s0.x + s1.x) + (s2.x + s3.x);
        ssy = (s0.y + s1.y) + (s2.y + s3.y);
    }
    __syncthreads();
    const float ivx = 1.f / fmaxf(sqrtf(ssx), 1e-8f);
    const float ivy = 1.f / fmaxf(sqrtf(ssy), 1e-8f);
#pragma unroll
    for (int j = 0; j < TPG; ++j) {
        wf[j].x = fmaxf(wf[j].x * ivx, 0.f);
        wf[j].y = fmaxf(wf[j].y * ivy, 0.f);
    }

    const float2 bv = b2[cq];
    const int bas = t0 - PAD_L + TPG * g;       // window base; bas % 16 == 1

#define LOADX2(m) ((!GUARD || ((unsigned)(m) < (unsigned)T_DIM))              \
                       ? xp2[(long long)(m) * C2] : make_float2(0.f, 0.f))

    // ---- circular window: slot(bas+i) = (1+i)&15 ----
    float2 xbuf[TPG];
#pragma unroll
    for (int i = 0; i < TPG; ++i) xbuf[(1 + i) & 15] = LOADX2(bas + i);

    float2 pfA[8], pfB[8];
#pragma unroll
    for (int i = 0; i < 8; ++i) pfA[i] = LOADX2(bas + 16 + i);   // sub0 inserts

    float2* __restrict__ slabw = slab + g * 512 + q;             // FIR write base
    const float2* __restrict__ slabr = slab + rp * 64 + q;       // reduce base

    // one FIR step; KO,j compile-time -> static xbuf slots, imm ds offsets
#define STEP(SOFF, KO, j, pf)                                                 \
    {                                                                         \
        float2 a0 = make_float2(0.f, 0.f), a1 = make_float2(0.f, 0.f);        \
        _Pragma("unroll")                                                     \
        for (int jt = 0; jt < TPG; jt += 2) {                                 \
            a0 = pkfma(wf[jt],     xbuf[(1 + (KO) + (j) + jt) & 15],     a0); \
            a1 = pkfma(wf[jt + 1], xbuf[(1 + (KO) + (j) + jt + 1) & 15], a1); \
        }                                                                     \
        slabw[(SOFF) + (j) * 64] = make_float2(a0.x + a1.x, a0.y + a1.y);     \
        xbuf[(1 + (KO) + (j)) & 15] = pf[(j)];                                \
    }

#define PHASE(SOFF, KO, pf)                                                   \
    STEP(SOFF, KO, 0, pf) STEP(SOFF, KO, 1, pf) STEP(SOFF, KO, 2, pf)         \
    STEP(SOFF, KO, 3, pf) STEP(SOFF, KO, 4, pf) STEP(SOFF, KO, 5, pf)         \
    STEP(SOFF, KO, 6, pf) STEP(SOFF, KO, 7, pf)

    // reduce 8 rows of slab SOFF -> out rows (t0+row0 .. +7); wave g does
    // rows rp, rp+1 (contiguous 512B LDS reads, coalesced float2 stores)
#define REDUCE(SOFF, row0)                                                    \
    {                                                                         \
        float2 r0 = bv, r1 = bv;                                              \
        _Pragma("unroll")                                                     \
        for (int gg = 0; gg < 4; ++gg) {                                      \
            const float2 u = slabr[(SOFF) + gg * 512];                        \
            const float2 v = slabr[(SOFF) + gg * 512 + 64];                   \
            r0.x += u.x; r0.y += u.y; r1.x += v.x; r1.y += v.y;               \
        }                                                                     \
        float2* __restrict__ op =                                             \
            out2 + (long long)(t0 + (row0) + rp) * C2 + cq;                   \
        op[0]  = r0;                                                          \
        op[C2] = r1;                                                          \
    }

    // ---- prologue: subtile 0 into slab A ----
    PHASE(0, 0, pfA)
#pragma unroll
    for (int i = 0; i < 8; ++i) pfB[i] = LOADX2(bas + 24 + i);   // sub1 inserts
    __syncthreads();

    // ---- main: 2 subtiles per iteration, ping-pong A/B, 2 barriers/iter ----
#pragma unroll 1
    for (int it = 0; it < 3; ++it) {
        const int kb = 16 * it;
#pragma unroll
        for (int j = 0; j < 8; ++j) pfA[j] = LOADX2(bas + 32 + kb + j);
        PHASE(SOFF_B, 8, pfB)        // subtile 2it+1 -> B
        REDUCE(0, kb)                // subtile 2it   (A)
        __syncthreads();
#pragma unroll
        for (int j = 0; j < 8; ++j) pfB[j] = LOADX2(bas + 40 + kb + j);
        PHASE(0, 0, pfA)             // subtile 2it+2 -> A
        REDUCE(SOFF_B, kb + 8)       // subtile 2it+1 (B)
        __syncthreads();
    }

    // ---- tail: subtile 7 ----
    PHASE(SOFF_B, 8, pfB)
    REDUCE(0, 48)
    __syncthreads();
    REDUCE(SOFF_B, 56)

#undef REDUCE
#undef PHASE
#undef STEP
#undef LOADX2
}

__global__ __launch_bounds__(256)
__attribute__((amdgpu_waves_per_eu(4, 4)))
void depthwise_fir_kernel(const float* __restrict__ x, const float* __restrict__ w,
                          const float* __restrict__ bia, float* __restrict__ out) {
    __shared__ float2 slab[2 * 4 * 8 * 64];                // 32 KiB, A|B ping-pong

    const int tid = threadIdx.x;
    const int g   = tid >> 6;                              // wave id = tap group
    const int q   = tid & 63;                              // float2-channel in block
    const int cq  = blockIdx.x * 64 + q;                   // global float2-channel
    const int t0  = blockIdx.y * KTILE;

    if (blockIdx.y == 0 || blockIdx.y == gridDim.y - 1)
        fir_body<true>((const float2*)x, (const float2*)w, (const float2*)bia,
                       (float2*)out, slab, cq, q, g, t0);
    else
        fir_body<false>((const float2*)x, (const float2*)w, (const float2*)bia,
                        (float2*)out, slab, cq, q, g, t0);
}

extern "C" void kernel_launch(void* const* d_in, const int* in_sizes, int n_in,
                              void* d_out, int out_size, void* d_ws, size_t ws_size,
                              hipStream_t stream) {
    const float* x = (const float*)d_in[0];   // [T, C]
    const float* w = (const float*)d_in[1];   // [FW, C]
    const float* b = (const float*)d_in[2];   // [C]
    float* out = (float*)d_out;               // [T, C]

    dim3 grid(C_DIM / 128, T_DIM / KTILE);    // 32 x 64 = 2048 blocks, c-fastest
    dim3 block(256);
    hipLaunchKernelGGL(depthwise_fir_kernel, grid, block, 0, stream, x, w, b, out);
}

// Round 15
// 42.822 us; speedup vs baseline: 1.3282x; 1.1404x over previous
//
#include <hip/hip_runtime.h>

// Depthwise temporal FIR (FW=64, SAME pad low=31/high=32), weight-norm +
// positivity clamp + bias. out[t,c] = b[c] + sum_f relu(w[f,c]/||w||) x[t-31+f,c]
//
// Round-15: R6's thread-per-channel register-streaming structure (no LDS, no
// shuffles, no reduction) with the allocator finally taken out of the game:
// amdgpu_waves_per_eu(2,2) pins occupancy at 2 waves/SIMD -> 256-VGPR budget
// for a ~160-reg live set (wf[64]+xbuf[64]+pf[16]). R6-R14 all lost ~2x VALU
// issue to AGPR-parking because every occupancy target implied budget < live
// set. Latency is hidden INTRA-wave: 8-deep prefetch = 512 FMA (>=1024 cy)
// between load issue and first use > ~900 cy HBM latency.
// KTILE=128: halo/2, grid = 16 x 32 = 512 blocks = exactly 2/CU (all
// co-resident, zero tail), c-blocks fastest (R11: L2 dedupes halo).

#define T_DIM 4096
#define C_DIM 4096
#define PAD_L 31
#define KTILE 128      // outputs per thread; circular buffer period = 64

template <bool GUARD>
__device__ __forceinline__ void fir_body(const float* __restrict__ x,
                                         const float* __restrict__ w,
                                         const float* __restrict__ b,
                                         float* __restrict__ out,
                                         int c, int t0) {
    const float* __restrict__ xp = x + c;          // channel column base
    float* __restrict__ op = out + (long long)t0 * C_DIM + c;

    // ---- weight-norm into registers (64 coalesced loads) ----
    float wf[64];
    float ss = 0.0f;
#pragma unroll
    for (int f = 0; f < 64; ++f) {
        wf[f] = w[f * C_DIM + c];
        ss = fmaf(wf[f], wf[f], ss);
    }
    const float inv = 1.0f / fmaxf(sqrtf(ss), 1e-8f);
#pragma unroll
    for (int f = 0; f < 64; ++f) wf[f] = fmaxf(wf[f] * inv, 0.0f);

    const float bv = b[c];
    const int base = t0 - PAD_L;                   // window start; t0 % 128 == 0

#define LOADX(m) ((!GUARD || ((unsigned)(m) < (unsigned)T_DIM))               \
                      ? xp[(long long)(m) * C_DIM] : 0.0f)

    // ---- circular window, invariant xbuf[m & 63] = x[m] ----
    // warm-up m = base..base+63 -> slot (i+33)&63  (base % 64 == 33)
    float xbuf[64];
#pragma unroll
    for (int i = 0; i < 64; ++i) xbuf[(i + 33) & 63] = LOADX(base + i);

    // insert for step kg is x[base + 64 + kg]; group G = inserts for steps
    // 8G..8G+7. Prologue: groups 0,1 into pfA,pfB.
    float pfA[8], pfB[8];
#pragma unroll
    for (int i = 0; i < 8; ++i) pfA[i] = LOADX(base + 64 + i);
#pragma unroll
    for (int i = 0; i < 8; ++i) pfB[i] = LOADX(base + 72 + i);

    // one step; k = kg & 63 is compile-time (period 64), kb = 64p runtime.
    // taps: slot(base+kg+f) = (k+f+33)&63; insert replaces f=0's slot.
#define FIR_STEP(k, src)                                                      \
    {                                                                         \
        float a0 = bv, a1 = 0.0f, a2 = 0.0f, a3 = 0.0f;                       \
        _Pragma("unroll")                                                     \
        for (int f = 0; f < 64; f += 4) {                                     \
            a0 = fmaf(wf[f + 0], xbuf[((k) + f + 33) & 63], a0);              \
            a1 = fmaf(wf[f + 1], xbuf[((k) + f + 34) & 63], a1);              \
            a2 = fmaf(wf[f + 2], xbuf[((k) + f + 35) & 63], a2);              \
            a3 = fmaf(wf[f + 3], xbuf[((k) + f + 36) & 63], a3);              \
        }                                                                     \
        xbuf[((k) + 33) & 63] = src[(k) & 7];                                 \
        __builtin_nontemporal_store((a0 + a1) + (a2 + a3),                    \
                                    op + (long long)(kb + (k)) * C_DIM);      \
    }

    // 8 steps + refill the just-drained buffer with group (kb/8 + gl + 2).
    // Refill is unconditional: worst m = base+207 = t0+176 <= 4016 for the
    // largest interior t0 (=3840); guarded tiles bounds-check via LOADX.
#define GROUP8(gl, src)                                                       \
    FIR_STEP((gl) * 8 + 0, src) FIR_STEP((gl) * 8 + 1, src)                   \
    FIR_STEP((gl) * 8 + 2, src) FIR_STEP((gl) * 8 + 3, src)                   \
    FIR_STEP((gl) * 8 + 4, src) FIR_STEP((gl) * 8 + 5, src)                   \
    FIR_STEP((gl) * 8 + 6, src) FIR_STEP((gl) * 8 + 7, src)                   \
    _Pragma("unroll")                                                         \
    for (int i = 0; i < 8; ++i) src[i] = LOADX(base + 80 + kb + (gl) * 8 + i);

    // two periods of 64 steps (slot arithmetic has period 64; t0 % 64 == 0)
#pragma unroll 1
    for (int p = 0; p < KTILE / 64; ++p) {
        const int kb = p * 64;
        GROUP8(0, pfA) GROUP8(1, pfB) GROUP8(2, pfA) GROUP8(3, pfB)
        GROUP8(4, pfA) GROUP8(5, pfB) GROUP8(6, pfA) GROUP8(7, pfB)
    }

#undef GROUP8
#undef FIR_STEP
#undef LOADX
}

__global__ __launch_bounds__(256)
__attribute__((amdgpu_waves_per_eu(2, 2)))
void depthwise_fir_kernel(const float* __restrict__ x, const float* __restrict__ w,
                          const float* __restrict__ b, float* __restrict__ out) {
    const int c  = blockIdx.x * 256 + threadIdx.x;   // c-blocks fastest (R11)
    const int t0 = blockIdx.y * KTILE;
    // zero-pad guard only at first/last time tile (block-uniform branch)
    if (blockIdx.y == 0 || blockIdx.y == gridDim.y - 1)
        fir_body<true>(x, w, b, out, c, t0);
    else
        fir_body<false>(x, w, b, out, c, t0);
}

extern "C" void kernel_launch(void* const* d_in, const int* in_sizes, int n_in,
                              void* d_out, int out_size, void* d_ws, size_t ws_size,
                              hipStream_t stream) {
    const float* x = (const float*)d_in[0];   // [T, C]
    const float* w = (const float*)d_in[1];   // [FW, C]
    const float* b = (const float*)d_in[2];   // [C]
    float* out = (float*)d_out;               // [T, C]

    dim3 grid(C_DIM / 256, T_DIM / KTILE);    // 16 x 32 = 512 blocks = 2/CU
    dim3 block(256);
    hipLaunchKernelGGL(depthwise_fir_kernel, grid, block, 0, stream, x, w, b, out);
}